// Round 2
// baseline (409.489 us; speedup 1.0000x reference)
//
#include <hip/hip_runtime.h>

typedef unsigned short u16;
typedef unsigned int   u32;
typedef __attribute__((ext_vector_type(8))) short bf16x8;
typedef __attribute__((ext_vector_type(4))) float f32x4;

#define SEQ 1024
#define BSZ 8
#define EMB 1024
#define NH  16
#define DH  64

__device__ __forceinline__ u16 f2bf(float f) {
    u32 u = __float_as_uint(f);
    u32 r = u + 0x7FFFu + ((u >> 16) & 1u);   // round-to-nearest-even
    return (u16)(r >> 16);
}

#define GLDS16(g, l) __builtin_amdgcn_global_load_lds( \
    (const __attribute__((address_space(1))) void*)(g), \
    (__attribute__((address_space(3))) void*)(l), 16, 0, 0)

// ---------------- convert x (fp32) -> xb (bf16) ----------------
__global__ __launch_bounds__(256) void cvt_x_k(const float* __restrict__ x,
                                               u16* __restrict__ xb) {
    size_t i = ((size_t)blockIdx.x * 256 + threadIdx.x) * 8;
    float4 a = *reinterpret_cast<const float4*>(x + i);
    float4 b = *reinterpret_cast<const float4*>(x + i + 4);
    union { u16 u[8]; uint4 v; } o;
    o.u[0]=f2bf(a.x); o.u[1]=f2bf(a.y); o.u[2]=f2bf(a.z); o.u[3]=f2bf(a.w);
    o.u[4]=f2bf(b.x); o.u[5]=f2bf(b.y); o.u[6]=f2bf(b.z); o.u[7]=f2bf(b.w);
    *reinterpret_cast<uint4*>(xb + i) = o.v;
}

// ------- convert + transpose weights: w (K,N) fp32 -> wT (N,K) bf16 -------
__global__ __launch_bounds__(256) void cvt_w_k(const float* __restrict__ w0, const float* __restrict__ w1,
                                               const float* __restrict__ w2, const float* __restrict__ w3,
                                               u16* __restrict__ wT) {
    int id  = blockIdx.x * 256 + threadIdx.x;
    int wi  = id >> 17;
    int rem = id & 131071;
    int kc  = rem >> 10;
    int n   = rem & 1023;
    const float* src = (wi==0) ? w0 : (wi==1) ? w1 : (wi==2) ? w2 : w3;
    union { u16 u[8]; uint4 v; } o;
    #pragma unroll
    for (int i = 0; i < 8; ++i) o.u[i] = f2bf(src[(size_t)(kc*8+i)*1024 + n]);
    *reinterpret_cast<uint4*>(wT + (size_t)wi*1048576 + (size_t)n*1024 + kc*8) = o.v;
}

// ---------------- bf16 GEMM, C = A(M,K) * BT(N,K)^T ----------------
// global_load_lds staging (m97 structure) + 2-bit source-side XOR swizzle.
// MODE 0: proj (z selects wq/wk/wv); writes qh/kh (head layout) and vt (d-major).
// MODE 1: out-proj; out[m][n] = acc + bias[n] (fp32).
template<int MODE>
__global__ __launch_bounds__(256) void gemm_bt(
    const u16* __restrict__ A, const u16* __restrict__ BT,
    const float* __restrict__ xres, const float* __restrict__ bias,
    u16* __restrict__ qh, u16* __restrict__ kh, u16* __restrict__ vt,
    float* __restrict__ outp)
{
    __shared__ u16 As[2][128*32];
    __shared__ u16 Bs[2][128*32];

    const int tid  = threadIdx.x;
    const int lane = tid & 63;
    const int wv   = tid >> 6;
    const int wm   = wv >> 1, wn = wv & 1;
    const int mBase = blockIdx.y * 128;
    const int nBase = blockIdx.x * 128;
    const int z = (MODE == 0) ? blockIdx.z : 0;
    const u16* Bm = BT + (size_t)z * (1024*1024);

    // staging: thread tid owns LDS 16B chunks tid and tid+256 (linear dest);
    // global source chunk XOR-swizzled by row&3 (read side applies same XOR)
    const int r0  = tid >> 2;
    const int cb0 = (tid & 3) ^ (r0 & 3);
    const u16* Ap0 = A  + (size_t)(mBase + r0)      * 1024 + cb0*8;
    const u16* Ap1 = A  + (size_t)(mBase + r0 + 64) * 1024 + cb0*8;   // (r0+64)&3 == r0&3
    const u16* Bp0 = Bm + (size_t)(nBase + r0)      * 1024 + cb0*8;
    const u16* Bp1 = Bm + (size_t)(nBase + r0 + 64) * 1024 + cb0*8;
    const int wb = wv * 512;     // wave-uniform LDS base (u16 units)

    f32x4 acc[4][4];
    #pragma unroll
    for (int i = 0; i < 4; ++i)
        #pragma unroll
        for (int j = 0; j < 4; ++j) acc[i][j] = (f32x4){0.f,0.f,0.f,0.f};

    const int arow = wm*64 + (lane & 15);
    const int brow = wn*64 + (lane & 15);
    const int kby  = (lane >> 4) * 16;            // byte col of 16B chunk
    const int aswz = (arow & 3) << 4;             // f*16 doesn't change &3
    const int bswz = (brow & 3) << 4;

    auto stg = [&](int buf, int kt) {
        const int ko = kt * 32;
        GLDS16(Ap0 + ko, &As[buf][wb]);
        GLDS16(Ap1 + ko, &As[buf][wb + 2048]);
        GLDS16(Bp0 + ko, &Bs[buf][wb]);
        GLDS16(Bp1 + ko, &Bs[buf][wb + 2048]);
    };

    stg(0, 0);
    int cur = 0;
    const int NT = 1024 / 32;
    for (int kt = 0; kt < NT; ++kt) {
        __syncthreads();                    // drains stage of buf[cur]
        if (kt + 1 < NT) stg(cur ^ 1, kt + 1);   // overlaps with compute below
        bf16x8 af[4], bf[4];
        #pragma unroll
        for (int f = 0; f < 4; ++f)
            af[f] = *reinterpret_cast<const bf16x8*>(
                reinterpret_cast<const char*>(&As[cur][(arow + f*16)*32]) + (kby ^ aswz));
        #pragma unroll
        for (int f = 0; f < 4; ++f)
            bf[f] = *reinterpret_cast<const bf16x8*>(
                reinterpret_cast<const char*>(&Bs[cur][(brow + f*16)*32]) + (kby ^ bswz));
        #pragma unroll
        for (int i = 0; i < 4; ++i)
            #pragma unroll
            for (int j = 0; j < 4; ++j)
                acc[i][j] = __builtin_amdgcn_mfma_f32_16x16x32_bf16(af[i], bf[j], acc[i][j], 0, 0, 0);
        cur ^= 1;
    }

    // epilogue: C layout col=lane&15, row=(lane>>4)*4+reg
    const int rbase = (lane >> 4) * 4;
    const int cbase = lane & 15;
    #pragma unroll
    for (int i = 0; i < 4; ++i) {
        #pragma unroll
        for (int j = 0; j < 4; ++j) {
            #pragma unroll
            for (int r = 0; r < 4; ++r) {
                const int m = mBase + wm*64 + i*16 + rbase + r;
                const int n = nBase + wn*64 + j*16 + cbase;
                const float v = acc[i][j][r];
                if (MODE == 0) {
                    const int s = m >> 3, bb = m & 7;
                    const int h = n >> 6, d  = n & 63;
                    if (z == 0)
                        qh[((size_t)(bb*NH + h)*SEQ + s)*DH + d] = f2bf(v * 0.125f);
                    else if (z == 1)
                        kh[((size_t)(bb*NH + h)*SEQ + s)*DH + d] = f2bf(v);
                    else  // V transposed: vt[bh][d][s]
                        vt[(size_t)(bb*NH + h)*(DH*SEQ) + (size_t)d*SEQ + s] =
                            f2bf(v + xres[(size_t)m*1024 + n]);
                } else {
                    outp[(size_t)m*1024 + n] = v + bias[n];
                }
            }
        }
    }
}

// ---------------- flash attention: barrier-free, global-direct K/V frags ----------------
// block = 4 waves x 32 q-rows = 128 q-rows; grid (SEQ/128, B*H)
__global__ __launch_bounds__(256, 3) void attn_k(
    const u16* __restrict__ qh, const u16* __restrict__ kh,
    const u16* __restrict__ vt, const float* __restrict__ mask,
    u16* __restrict__ ctx)
{
    __shared__ u16 Pl[128*64];   // [q][key] bf16, rows XOR-swizzled by (q&7)<<4

    const int tid  = threadIdx.x;
    const int lane = tid & 63;
    const int wv   = tid >> 6;
    const int l15  = lane & 15;
    const int lg   = lane >> 4;
    const int bh = blockIdx.y;
    const int b  = bh >> 4;
    const int h  = bh & 15;
    const int qbase = blockIdx.x * 128;
    const size_t bhOff = (size_t)bh * (SEQ*DH);

    // Q fragments: aq[fq][kk], row = qbase + wv*32 + fq*16 + l15
    bf16x8 aq[2][2];
    #pragma unroll
    for (int fq = 0; fq < 2; ++fq)
        #pragma unroll
        for (int kk = 0; kk < 2; ++kk)
            aq[fq][kk] = *reinterpret_cast<const bf16x8*>(
                qh + bhOff + (size_t)(qbase + wv*32 + fq*16 + l15)*DH + kk*32 + lg*8);

    f32x4 o[2][4];
    float mrun[2][4], lrun[2][4];
    #pragma unroll
    for (int fq = 0; fq < 2; ++fq) {
        #pragma unroll
        for (int fd = 0; fd < 4; ++fd) o[fq][fd] = (f32x4){0.f,0.f,0.f,0.f};
        #pragma unroll
        for (int j = 0; j < 4; ++j) { mrun[fq][j] = -1e30f; lrun[fq][j] = 0.f; }
    }

    bf16x8 ones;
    #pragma unroll
    for (int i = 0; i < 8; ++i) ones[i] = (short)0x3F80;   // bf16 1.0

    const u16* kPtr = kh + bhOff + (size_t)l15*DH + lg*8;   // key row l15, d col lg*8
    const u16* vPtr = vt + bhOff + (size_t)l15*SEQ + lg*8;  // d row l15, key col lg*8
    const float* mPtr = mask + (size_t)b*SEQ + l15;
    const int pq = wv*32;

    for (int kt = 0; kt < 16; ++kt) {
        const int jb = kt * 64;
        // ---- K fragments (B-operand of QK^T), direct from global ----
        bf16x8 kf[4][2];
        #pragma unroll
        for (int fn = 0; fn < 4; ++fn)
            #pragma unroll
            for (int kk = 0; kk < 2; ++kk)
                kf[fn][kk] = *reinterpret_cast<const bf16x8*>(kPtr + (size_t)(jb + fn*16)*DH + kk*32);
        // ---- scores ----
        f32x4 sc[2][4];
        #pragma unroll
        for (int fq = 0; fq < 2; ++fq)
            #pragma unroll
            for (int fn = 0; fn < 4; ++fn) {
                f32x4 t = __builtin_amdgcn_mfma_f32_16x16x32_bf16(aq[fq][0], kf[fn][0],
                            (f32x4){0.f,0.f,0.f,0.f}, 0, 0, 0);
                sc[fq][fn] = __builtin_amdgcn_mfma_f32_16x16x32_bf16(aq[fq][1], kf[fn][1], t, 0, 0, 0);
            }
        // ---- additive key-padding mask ----
        float mv[4];
        #pragma unroll
        for (int fn = 0; fn < 4; ++fn) mv[fn] = mPtr[jb + fn*16];
        #pragma unroll
        for (int fq = 0; fq < 2; ++fq)
            #pragma unroll
            for (int fn = 0; fn < 4; ++fn)
                #pragma unroll
                for (int j = 0; j < 4; ++j) sc[fq][fn][j] += mv[fn];
        // ---- tile max (reduce over key: fn in-reg + 16 lanes) ----
        float mx[2][4];
        #pragma unroll
        for (int fq = 0; fq < 2; ++fq)
            #pragma unroll
            for (int j = 0; j < 4; ++j)
                mx[fq][j] = fmaxf(fmaxf(sc[fq][0][j], sc[fq][1][j]),
                                  fmaxf(sc[fq][2][j], sc[fq][3][j]));
        #pragma unroll
        for (int off = 1; off < 16; off <<= 1)
            #pragma unroll
            for (int fq = 0; fq < 2; ++fq)
                #pragma unroll
                for (int j = 0; j < 4; ++j)
                    mx[fq][j] = fmaxf(mx[fq][j], __shfl_xor(mx[fq][j], off));
        // ---- defer-max: rescale only if max grew past threshold ----
        int need = 0;
        #pragma unroll
        for (int fq = 0; fq < 2; ++fq)
            #pragma unroll
            for (int j = 0; j < 4; ++j)
                need |= (mx[fq][j] > mrun[fq][j] + 8.0f);
        if (__any(need)) {
            #pragma unroll
            for (int fq = 0; fq < 2; ++fq)
                #pragma unroll
                for (int j = 0; j < 4; ++j) {
                    const float mn = fmaxf(mrun[fq][j], mx[fq][j]);
                    const float s  = __expf(mrun[fq][j] - mn);
                    mrun[fq][j] = mn;
                    lrun[fq][j] *= s;
                    #pragma unroll
                    for (int fd = 0; fd < 4; ++fd) o[fq][fd][j] *= s;
                }
        }
        // ---- V fragments (issue early; latency hides under P round-trip) ----
        bf16x8 vf[4][2];
        #pragma unroll
        for (int fd = 0; fd < 4; ++fd)
            #pragma unroll
            for (int kk = 0; kk < 2; ++kk)
                vf[fd][kk] = *reinterpret_cast<const bf16x8*>(vPtr + (size_t)(fd*16)*SEQ + jb + kk*32);
        // ---- P = exp(sc - mrun) -> LDS bf16 (truncate; wave-private rows) ----
        #pragma unroll
        for (int fq = 0; fq < 2; ++fq)
            #pragma unroll
            for (int fn = 0; fn < 4; ++fn)
                #pragma unroll
                for (int j = 0; j < 4; ++j) {
                    const float p = __expf(sc[fq][fn][j] - mrun[fq][j]);
                    const int q = pq + fq*16 + lg*4 + j;
                    const int off = (q*128 + (fn*16 + l15)*2) ^ ((q & 7) << 4);
                    *reinterpret_cast<u16*>(reinterpret_cast<char*>(Pl) + off) =
                        (u16)(__float_as_uint(p) >> 16);
                }
        asm volatile("s_waitcnt lgkmcnt(0)" ::: "memory");
        // ---- P A-fragments back from LDS ----
        bf16x8 pa[2][2];
        #pragma unroll
        for (int fq = 0; fq < 2; ++fq)
            #pragma unroll
            for (int kk = 0; kk < 2; ++kk) {
                const int q = pq + fq*16 + l15;
                const int off = (q*128 + (kk*32 + lg*8)*2) ^ ((q & 7) << 4);
                pa[fq][kk] = *reinterpret_cast<const bf16x8*>(reinterpret_cast<char*>(Pl) + off);
            }
        // ---- row-sums via ones-MFMA (layout matches lrun rows) ----
        #pragma unroll
        for (int fq = 0; fq < 2; ++fq) {
            f32x4 racc = __builtin_amdgcn_mfma_f32_16x16x32_bf16(pa[fq][0], ones,
                            (f32x4){0.f,0.f,0.f,0.f}, 0, 0, 0);
            racc = __builtin_amdgcn_mfma_f32_16x16x32_bf16(pa[fq][1], ones, racc, 0, 0, 0);
            #pragma unroll
            for (int j = 0; j < 4; ++j) lrun[fq][j] += racc[j];
        }
        // ---- O += P * V ----
        #pragma unroll
        for (int fq = 0; fq < 2; ++fq)
            #pragma unroll
            for (int fd = 0; fd < 4; ++fd) {
                o[fq][fd] = __builtin_amdgcn_mfma_f32_16x16x32_bf16(pa[fq][0], vf[fd][0], o[fq][fd], 0, 0, 0);
                o[fq][fd] = __builtin_amdgcn_mfma_f32_16x16x32_bf16(pa[fq][1], vf[fd][1], o[fq][fd], 0, 0, 0);
            }
    }

    // ---- epilogue: ctx[(s*B+b)][h*64+d] bf16 ----
    #pragma unroll
    for (int fq = 0; fq < 2; ++fq)
        #pragma unroll
        for (int j = 0; j < 4; ++j) {
            const float inv = 1.0f / lrun[fq][j];
            const int s = qbase + wv*32 + fq*16 + lg*4 + j;
            #pragma unroll
            for (int fd = 0; fd < 4; ++fd) {
                const int d = fd*16 + l15;
                ctx[((size_t)(s*BSZ + b))*EMB + h*DH + d] = f2bf(o[fq][fd][j] * inv);
            }
        }
}

extern "C" void kernel_launch(void* const* d_in, const int* in_sizes, int n_in,
                              void* d_out, int out_size, void* d_ws, size_t ws_size,
                              hipStream_t stream) {
    const float* x    = (const float*)d_in[0];
    const float* mask = (const float*)d_in[1];
    const float* w_q  = (const float*)d_in[2];
    const float* w_k  = (const float*)d_in[3];
    const float* w_v  = (const float*)d_in[4];
    const float* w_o  = (const float*)d_in[5];
    const float* b_o  = (const float*)d_in[6];

    char* ws = (char*)d_ws;
    u16* xb  = (u16*)(ws);                        // 16 MB
    u16* wT  = (u16*)(ws + ((size_t)16 << 20));   // 8 MB
    u16* qh  = (u16*)(ws + ((size_t)24 << 20));   // 16 MB
    u16* kh  = (u16*)(ws + ((size_t)40 << 20));   // 16 MB
    u16* vt  = (u16*)(ws + ((size_t)56 << 20));   // 16 MB (V transposed per head)
    u16* ctx = (u16*)(ws + ((size_t)72 << 20));   // 16 MB
    float* outp = (float*)d_out;

    cvt_x_k<<<4096, 256, 0, stream>>>(x, xb);
    cvt_w_k<<<2048, 256, 0, stream>>>(w_q, w_k, w_v, w_o, wT);
    gemm_bt<0><<<dim3(8, 64, 3), 256, 0, stream>>>(xb, wT, x, nullptr, qh, kh, vt, nullptr);
    attn_k<<<dim3(8, 128), 256, 0, stream>>>(qh, kh, vt, mask, ctx);
    gemm_bt<1><<<dim3(8, 64, 1), 256, 0, stream>>>(ctx, wT + (size_t)3*1048576, nullptr, b_o,
                                                   nullptr, nullptr, nullptr, outp);
}

// Round 3
// 253.054 us; speedup vs baseline: 1.6182x; 1.6182x over previous
//
#include <hip/hip_runtime.h>

typedef unsigned short u16;
typedef unsigned int   u32;
typedef __attribute__((ext_vector_type(8))) short bf16x8;
typedef __attribute__((ext_vector_type(4))) float f32x4;

#define SEQ 1024
#define BSZ 8
#define EMB 1024
#define NH  16
#define DH  64
#define KVB 64

__device__ __forceinline__ u16 f2bf(float f) {
    u32 u = __float_as_uint(f);
    u32 r = u + 0x7FFFu + ((u >> 16) & 1u);   // round-to-nearest-even
    return (u16)(r >> 16);
}

#define GLDS16(g, l) __builtin_amdgcn_global_load_lds( \
    (const __attribute__((address_space(1))) void*)(g), \
    (__attribute__((address_space(3))) void*)(l), 16, 0, 0)

// ---------------- convert x (fp32) -> xb (bf16) ----------------
__global__ __launch_bounds__(256) void cvt_x_k(const float* __restrict__ x,
                                               u16* __restrict__ xb) {
    size_t i = ((size_t)blockIdx.x * 256 + threadIdx.x) * 8;
    float4 a = *reinterpret_cast<const float4*>(x + i);
    float4 b = *reinterpret_cast<const float4*>(x + i + 4);
    union { u16 u[8]; uint4 v; } o;
    o.u[0]=f2bf(a.x); o.u[1]=f2bf(a.y); o.u[2]=f2bf(a.z); o.u[3]=f2bf(a.w);
    o.u[4]=f2bf(b.x); o.u[5]=f2bf(b.y); o.u[6]=f2bf(b.z); o.u[7]=f2bf(b.w);
    *reinterpret_cast<uint4*>(xb + i) = o.v;
}

// ------- convert + transpose weights: w (K,N) fp32 -> wT (N,K) bf16 -------
__global__ __launch_bounds__(256) void cvt_w_k(const float* __restrict__ w0, const float* __restrict__ w1,
                                               const float* __restrict__ w2, const float* __restrict__ w3,
                                               u16* __restrict__ wT) {
    int id  = blockIdx.x * 256 + threadIdx.x;
    int wi  = id >> 17;
    int rem = id & 131071;
    int kc  = rem >> 10;
    int n   = rem & 1023;
    const float* src = (wi==0) ? w0 : (wi==1) ? w1 : (wi==2) ? w2 : w3;
    union { u16 u[8]; uint4 v; } o;
    #pragma unroll
    for (int i = 0; i < 8; ++i) o.u[i] = f2bf(src[(size_t)(kc*8+i)*1024 + n]);
    *reinterpret_cast<uint4*>(wT + (size_t)wi*1048576 + (size_t)n*1024 + kc*8) = o.v;
}

// ---------------- bf16 GEMM, C = A(M,K) * BT(N,K)^T ----------------
template<int MODE>
__global__ __launch_bounds__(256) void gemm_bt(
    const u16* __restrict__ A, const u16* __restrict__ BT,
    const float* __restrict__ xres, const float* __restrict__ bias,
    u16* __restrict__ qh, u16* __restrict__ kh, u16* __restrict__ vh,
    float* __restrict__ outp)
{
    __shared__ u16 As[2][128*32];
    __shared__ u16 Bs[2][128*32];

    const int tid  = threadIdx.x;
    const int lane = tid & 63;
    const int wv   = tid >> 6;
    const int wm   = wv >> 1, wn = wv & 1;
    const int mBase = blockIdx.y * 128;
    const int nBase = blockIdx.x * 128;
    const int z = (MODE == 0) ? blockIdx.z : 0;
    const u16* Bm = BT + (size_t)z * (1024*1024);

    const int r0  = tid >> 2;
    const int cb0 = (tid & 3) ^ (r0 & 3);
    const u16* Ap0 = A  + (size_t)(mBase + r0)      * 1024 + cb0*8;
    const u16* Ap1 = A  + (size_t)(mBase + r0 + 64) * 1024 + cb0*8;
    const u16* Bp0 = Bm + (size_t)(nBase + r0)      * 1024 + cb0*8;
    const u16* Bp1 = Bm + (size_t)(nBase + r0 + 64) * 1024 + cb0*8;
    const int wb = wv * 512;

    f32x4 acc[4][4];
    #pragma unroll
    for (int i = 0; i < 4; ++i)
        #pragma unroll
        for (int j = 0; j < 4; ++j) acc[i][j] = (f32x4){0.f,0.f,0.f,0.f};

    const int arow = wm*64 + (lane & 15);
    const int brow = wn*64 + (lane & 15);
    const int kby  = (lane >> 4) * 16;
    const int aswz = (arow & 3) << 4;
    const int bswz = (brow & 3) << 4;

    auto stg = [&](int buf, int kt) {
        const int ko = kt * 32;
        GLDS16(Ap0 + ko, &As[buf][wb]);
        GLDS16(Ap1 + ko, &As[buf][wb + 2048]);
        GLDS16(Bp0 + ko, &Bs[buf][wb]);
        GLDS16(Bp1 + ko, &Bs[buf][wb + 2048]);
    };

    stg(0, 0);
    int cur = 0;
    const int NT = 1024 / 32;
    for (int kt = 0; kt < NT; ++kt) {
        __syncthreads();
        if (kt + 1 < NT) stg(cur ^ 1, kt + 1);
        bf16x8 af[4], bf[4];
        #pragma unroll
        for (int f = 0; f < 4; ++f)
            af[f] = *reinterpret_cast<const bf16x8*>(
                reinterpret_cast<const char*>(&As[cur][(arow + f*16)*32]) + (kby ^ aswz));
        #pragma unroll
        for (int f = 0; f < 4; ++f)
            bf[f] = *reinterpret_cast<const bf16x8*>(
                reinterpret_cast<const char*>(&Bs[cur][(brow + f*16)*32]) + (kby ^ bswz));
        #pragma unroll
        for (int i = 0; i < 4; ++i)
            #pragma unroll
            for (int j = 0; j < 4; ++j)
                acc[i][j] = __builtin_amdgcn_mfma_f32_16x16x32_bf16(af[i], bf[j], acc[i][j], 0, 0, 0);
        cur ^= 1;
    }

    const int rbase = (lane >> 4) * 4;
    const int cbase = lane & 15;
    #pragma unroll
    for (int i = 0; i < 4; ++i) {
        #pragma unroll
        for (int j = 0; j < 4; ++j) {
            #pragma unroll
            for (int r = 0; r < 4; ++r) {
                const int m = mBase + wm*64 + i*16 + rbase + r;
                const int n = nBase + wn*64 + j*16 + cbase;
                const float v = acc[i][j][r];
                if (MODE == 0) {
                    const int s = m >> 3, bb = m & 7;
                    const int h = n >> 6, d  = n & 63;
                    const size_t oidx = ((size_t)(bb*NH + h)*SEQ + s)*DH + d;
                    if (z == 0)      qh[oidx] = f2bf(v * 0.125f);
                    else if (z == 1) kh[oidx] = f2bf(v);
                    else             vh[oidx] = f2bf(v + xres[(size_t)m*1024 + n]);
                } else {
                    outp[(size_t)m*1024 + n] = v + bias[n];
                }
            }
        }
    }
}

// ---------------- transpose V: vh[bh][s][d] -> vt[bh][d][s] ----------------
__global__ __launch_bounds__(256) void vtrans_k(const u16* __restrict__ vh,
                                                u16* __restrict__ vt) {
    __shared__ u16 T[64*64];
    const int tid = threadIdx.x;
    const int s0 = blockIdx.x * 64;
    const size_t base = (size_t)blockIdx.y * (SEQ*DH);
    #pragma unroll
    for (int k = 0; k < 2; ++k) {
        const int idx = k*256 + tid;
        const int r = idx >> 3, c = idx & 7;
        uint4 v = *reinterpret_cast<const uint4*>(vh + base + (size_t)(s0 + r)*DH + c*8);
        const int cs = c ^ (r & 7) ^ ((r >> 3) & 7);
        *reinterpret_cast<uint4*>(reinterpret_cast<char*>(T) + r*128 + cs*16) = v;
    }
    __syncthreads();
    #pragma unroll
    for (int k = 0; k < 2; ++k) {
        const int idx = k*256 + tid;
        const int d = idx >> 3, kc = idx & 7;
        union { u16 u[8]; uint4 v; } o;
        #pragma unroll
        for (int i = 0; i < 8; ++i) {
            const int s = kc*8 + i;
            const int ch = (d >> 3) ^ (s & 7) ^ ((s >> 3) & 7);
            o.u[i] = T[s*64 + ch*8 + (d & 7)];
        }
        *reinterpret_cast<uint4*>(vt + base + (size_t)d*SEQ + s0 + kc*8) = o.v;
    }
}

// ---------------- flash attention: LDS-staged K/V (GLDS16 + swizzle) ----------------
// block = 4 waves x 32 q-rows = 128 q; grid (8, 128), XCD-remapped inside
__global__ __launch_bounds__(256, 2) void attn_k(
    const u16* __restrict__ qh, const u16* __restrict__ kh,
    const u16* __restrict__ vt, const float* __restrict__ mask,
    u16* __restrict__ ctx)
{
    __shared__ u16 Kl[2][KVB*64];   // [key][d], chunk-swizzled by key&7
    __shared__ u16 Vl[2][KVB*64];   // [d][key], chunk-swizzled by d&7
    __shared__ u16 Pl[128*64];      // [q][key], chunk-swizzled by q&7

    const int tid  = threadIdx.x;
    const int lane = tid & 63;
    const int wv   = tid >> 6;
    const int l15  = lane & 15;
    const int lg   = lane >> 4;

    // XCD remap: dispatch id d0, xcd = d0&7 owns bh in [xcd*16, xcd*16+16)
    const int d0 = blockIdx.y * 8 + blockIdx.x;
    const int bh = (d0 & 7) * 16 + (d0 >> 6);
    const int qt = (d0 >> 3) & 7;
    const int b  = bh >> 4;
    const int h  = bh & 15;
    const int qbase = qt * 128;
    const size_t bhOff = (size_t)bh * (SEQ*DH);

    // staging geometry: chunk idx = s*256+tid; row r = idx>>3, chunk c = idx&7
    const int rS = tid >> 3;                    // 0..31 (s=0); +32 for s=1
    const int cS = (tid & 7) ^ (rS & 7);        // pre-swizzled source chunk
    const u16* kSrc = kh + bhOff + (size_t)rS*DH  + cS*8;
    const u16* vSrc = vt + bhOff + (size_t)rS*SEQ + cS*8;
    const int ldst = wv * 512;                  // u16 offset of wave segment

    // Q fragments: aq[fq][kk]
    bf16x8 aq[2][2];
    #pragma unroll
    for (int fq = 0; fq < 2; ++fq)
        #pragma unroll
        for (int kk = 0; kk < 2; ++kk)
            aq[fq][kk] = *reinterpret_cast<const bf16x8*>(
                qh + bhOff + (size_t)(qbase + wv*32 + fq*16 + l15)*DH + kk*32 + lg*8);

    f32x4 o[2][4];
    float mrun[2][4], lrun[2][4];
    #pragma unroll
    for (int fq = 0; fq < 2; ++fq) {
        #pragma unroll
        for (int fd = 0; fd < 4; ++fd) o[fq][fd] = (f32x4){0.f,0.f,0.f,0.f};
        #pragma unroll
        for (int j = 0; j < 4; ++j) { mrun[fq][j] = -1e30f; lrun[fq][j] = 0.f; }
    }

    bf16x8 ones;
    #pragma unroll
    for (int i = 0; i < 8; ++i) ones[i] = (short)0x3F80;

    // fragment read chunk-offsets (bytes): chunk = (kk*4+lg) ^ (row&7), row&7 == l15&7
    const int co0 = ((lg)     ^ (l15 & 7)) << 4;
    const int co1 = ((4 + lg) ^ (l15 & 7)) << 4;
    const float* mPtr = mask + (size_t)b*SEQ + l15;
    const int pq = wv*32;

    auto stage = [&](int buf, int kt) {
        const int jb = kt * KVB;
        GLDS16(kSrc + (size_t)jb*DH,        &Kl[buf][ldst]);
        GLDS16(kSrc + (size_t)(jb+32)*DH,   &Kl[buf][2048 + ldst]);
        GLDS16(vSrc + jb,                   &Vl[buf][ldst]);
        GLDS16(vSrc + 32*SEQ + jb,          &Vl[buf][2048 + ldst]);
    };

    stage(0, 0);
    int cur = 0;

    for (int kt = 0; kt < 16; ++kt) {
        __syncthreads();                      // drains stage of buf[cur] + prior reads
        if (kt + 1 < 16) stage(cur ^ 1, kt + 1);
        const int jb = kt * KVB;

        // ---- scores: S = Q * K^T ----
        f32x4 sc[2][4];
        const char* kb = reinterpret_cast<const char*>(&Kl[cur][0]) + l15*128;
        #pragma unroll
        for (int fn = 0; fn < 4; ++fn) {
            bf16x8 k0 = *reinterpret_cast<const bf16x8*>(kb + fn*2048 + co0);
            bf16x8 k1 = *reinterpret_cast<const bf16x8*>(kb + fn*2048 + co1);
            #pragma unroll
            for (int fq = 0; fq < 2; ++fq) {
                f32x4 t = __builtin_amdgcn_mfma_f32_16x16x32_bf16(aq[fq][0], k0,
                            (f32x4){0.f,0.f,0.f,0.f}, 0, 0, 0);
                sc[fq][fn] = __builtin_amdgcn_mfma_f32_16x16x32_bf16(aq[fq][1], k1, t, 0, 0, 0);
            }
        }
        // ---- additive key-padding mask ----
        float mv[4];
        #pragma unroll
        for (int fn = 0; fn < 4; ++fn) mv[fn] = mPtr[jb + fn*16];
        #pragma unroll
        for (int fq = 0; fq < 2; ++fq)
            #pragma unroll
            for (int fn = 0; fn < 4; ++fn)
                #pragma unroll
                for (int j = 0; j < 4; ++j) sc[fq][fn][j] += mv[fn];
        // ---- tile max ----
        float mx[2][4];
        #pragma unroll
        for (int fq = 0; fq < 2; ++fq)
            #pragma unroll
            for (int j = 0; j < 4; ++j)
                mx[fq][j] = fmaxf(fmaxf(sc[fq][0][j], sc[fq][1][j]),
                                  fmaxf(sc[fq][2][j], sc[fq][3][j]));
        #pragma unroll
        for (int off = 1; off < 16; off <<= 1)
            #pragma unroll
            for (int fq = 0; fq < 2; ++fq)
                #pragma unroll
                for (int j = 0; j < 4; ++j)
                    mx[fq][j] = fmaxf(mx[fq][j], __shfl_xor(mx[fq][j], off));
        // ---- defer-max rescale ----
        int need = 0;
        #pragma unroll
        for (int fq = 0; fq < 2; ++fq)
            #pragma unroll
            for (int j = 0; j < 4; ++j)
                need |= (mx[fq][j] > mrun[fq][j] + 8.0f);
        if (__any(need)) {
            #pragma unroll
            for (int fq = 0; fq < 2; ++fq)
                #pragma unroll
                for (int j = 0; j < 4; ++j) {
                    const float mn = fmaxf(mrun[fq][j], mx[fq][j]);
                    const float s  = __expf(mrun[fq][j] - mn);
                    mrun[fq][j] = mn;
                    lrun[fq][j] *= s;
                    #pragma unroll
                    for (int fd = 0; fd < 4; ++fd) o[fq][fd][j] *= s;
                }
        }
        // ---- P = exp(sc - mrun) -> LDS (truncate to bf16; wave-private rows) ----
        #pragma unroll
        for (int fq = 0; fq < 2; ++fq)
            #pragma unroll
            for (int fn = 0; fn < 4; ++fn)
                #pragma unroll
                for (int j = 0; j < 4; ++j) {
                    const float p = __expf(sc[fq][fn][j] - mrun[fq][j]);
                    const int q = pq + fq*16 + lg*4 + j;
                    const int off = (q*128 + (fn*16 + l15)*2) ^ ((q & 7) << 4);
                    *reinterpret_cast<u16*>(reinterpret_cast<char*>(Pl) + off) =
                        (u16)(__float_as_uint(p) >> 16);
                }
        asm volatile("s_waitcnt lgkmcnt(0)" ::: "memory");
        __builtin_amdgcn_sched_barrier(0);
        // ---- P A-fragments back from LDS ----
        bf16x8 pa[2][2];
        #pragma unroll
        for (int fq = 0; fq < 2; ++fq) {
            const int q = pq + fq*16 + l15;
            pa[fq][0] = *reinterpret_cast<const bf16x8*>(
                reinterpret_cast<char*>(Pl) + q*128 + co0);
            pa[fq][1] = *reinterpret_cast<const bf16x8*>(
                reinterpret_cast<char*>(Pl) + q*128 + co1);
        }
        // ---- row-sums via ones-MFMA ----
        #pragma unroll
        for (int fq = 0; fq < 2; ++fq) {
            f32x4 racc = __builtin_amdgcn_mfma_f32_16x16x32_bf16(pa[fq][0], ones,
                            (f32x4){0.f,0.f,0.f,0.f}, 0, 0, 0);
            racc = __builtin_amdgcn_mfma_f32_16x16x32_bf16(pa[fq][1], ones, racc, 0, 0, 0);
            #pragma unroll
            for (int j = 0; j < 4; ++j) lrun[fq][j] += racc[j];
        }
        // ---- O += P * V ----
        const char* vb = reinterpret_cast<const char*>(&Vl[cur][0]) + l15*128;
        #pragma unroll
        for (int fd = 0; fd < 4; ++fd) {
            bf16x8 v0 = *reinterpret_cast<const bf16x8*>(vb + fd*2048 + co0);
            bf16x8 v1 = *reinterpret_cast<const bf16x8*>(vb + fd*2048 + co1);
            #pragma unroll
            for (int fq = 0; fq < 2; ++fq) {
                o[fq][fd] = __builtin_amdgcn_mfma_f32_16x16x32_bf16(pa[fq][0], v0, o[fq][fd], 0, 0, 0);
                o[fq][fd] = __builtin_amdgcn_mfma_f32_16x16x32_bf16(pa[fq][1], v1, o[fq][fd], 0, 0, 0);
            }
        }
        cur ^= 1;
    }

    // ---- epilogue: ctx[(s*B+b)][h*64+d] bf16 ----
    #pragma unroll
    for (int fq = 0; fq < 2; ++fq)
        #pragma unroll
        for (int j = 0; j < 4; ++j) {
            const float inv = 1.0f / lrun[fq][j];
            const int s = qbase + wv*32 + fq*16 + lg*4 + j;
            #pragma unroll
            for (int fd = 0; fd < 4; ++fd) {
                const int d = fd*16 + l15;
                ctx[((size_t)(s*BSZ + b))*EMB + h*DH + d] = f2bf(o[fq][fd][j] * inv);
            }
        }
}

extern "C" void kernel_launch(void* const* d_in, const int* in_sizes, int n_in,
                              void* d_out, int out_size, void* d_ws, size_t ws_size,
                              hipStream_t stream) {
    const float* x    = (const float*)d_in[0];
    const float* mask = (const float*)d_in[1];
    const float* w_q  = (const float*)d_in[2];
    const float* w_k  = (const float*)d_in[3];
    const float* w_v  = (const float*)d_in[4];
    const float* w_o  = (const float*)d_in[5];
    const float* b_o  = (const float*)d_in[6];

    char* ws = (char*)d_ws;
    u16* xb  = (u16*)(ws);                        // 16 MB
    u16* wT  = (u16*)(ws + ((size_t)16 << 20));   // 8 MB
    u16* qh  = (u16*)(ws + ((size_t)24 << 20));   // 16 MB
    u16* kh  = (u16*)(ws + ((size_t)40 << 20));   // 16 MB
    u16* vt  = (u16*)(ws + ((size_t)56 << 20));   // 16 MB (V transposed)
    u16* vh  = (u16*)(ws + ((size_t)72 << 20));   // 16 MB
    u16* ctx = vh;                                // vh dead after vtrans
    float* outp = (float*)d_out;

    cvt_x_k<<<4096, 256, 0, stream>>>(x, xb);
    cvt_w_k<<<2048, 256, 0, stream>>>(w_q, w_k, w_v, w_o, wT);
    gemm_bt<0><<<dim3(8, 64, 3), 256, 0, stream>>>(xb, wT, x, nullptr, qh, kh, vh, nullptr);
    vtrans_k<<<dim3(16, 128), 256, 0, stream>>>(vh, vt);
    attn_k<<<dim3(8, 128), 256, 0, stream>>>(qh, kh, vt, mask, ctx);
    gemm_bt<1><<<dim3(8, 64, 1), 256, 0, stream>>>(ctx, wT + (size_t)3*1048576, nullptr, b_o,
                                                   nullptr, nullptr, nullptr, outp);
}